// Round 3
// baseline (4551.664 us; speedup 1.0000x reference)
//
#include <hip/hip_runtime.h>
#include <stdint.h>

#define HDIM 1024
#define ODIM 768
#define BDIM 256
#define TLEN 256
#define G3 (3*HDIM)

typedef __attribute__((ext_vector_type(4))) float f32x4;
typedef __attribute__((ext_vector_type(8))) short s16x8;
typedef __attribute__((ext_vector_type(2))) unsigned long long u64x2;

#define SENT64 0xFFFFFFFFFFFFFFFFull

static __device__ __forceinline__ unsigned short f2bf(float f) {
  uint32_t u = __builtin_bit_cast(uint32_t, f);
  return (unsigned short)((u + 0x7fffu + ((u >> 16) & 1u)) >> 16);
}

// ---------------- prep kernels ----------------

__global__ void k_f32_to_bf16(const float* __restrict__ in, unsigned short* __restrict__ out, int n4) {
  int i = blockIdx.x * 256 + threadIdx.x;
  if (i >= n4) return;
  float4 v = ((const float4*)in)[i];
  ushort4 o;
  o.x = f2bf(v.x); o.y = f2bf(v.y); o.z = f2bf(v.z); o.w = f2bf(v.w);
  ((ushort4*)out)[i] = o;
}

// in [R][C] f32 -> out [C][R] bf16
__global__ void k_transpose_f32_bf16(const float* __restrict__ in, unsigned short* __restrict__ out, int R, int C) {
  __shared__ float tile[32][33];
  int c0 = blockIdx.x * 32, r0 = blockIdx.y * 32;
  int tx = threadIdx.x, ty = threadIdx.y;
  #pragma unroll
  for (int i = 0; i < 32; i += 8)
    tile[ty + i][tx] = in[(size_t)(r0 + ty + i) * C + (c0 + tx)];
  __syncthreads();
  #pragma unroll
  for (int i = 0; i < 32; i += 8)
    out[(size_t)(c0 + ty + i) * R + (r0 + tx)] = f2bf(tile[tx][ty + i]);
}

// b_comb[c] = b_ih[c] + sum_o w_ih[c][o] * b_fc[o]   (fp32)
__global__ void k_bcomb(const float* __restrict__ w_ih, const float* __restrict__ b_ih,
                        const float* __restrict__ b_fc, float* __restrict__ bc) {
  int gw = (blockIdx.x * 256 + threadIdx.x) >> 6;
  int lane = threadIdx.x & 63;
  if (gw >= G3) return;
  const float* row = w_ih + (size_t)gw * ODIM;
  float s = 0.f;
  for (int o = lane; o < ODIM; o += 64) s += row[o] * b_fc[o];
  #pragma unroll
  for (int off = 32; off; off >>= 1) s += __shfl_down(s, off);
  if (lane == 0) bc[gw] = s + b_ih[gw];
}

// ---------------- generic bf16 GEMM: C[M][N] = A[M][K] * Bm[N][K]^T (+bias) ----------------
template<bool OUT_BF16, bool ADD_BIAS>
__global__ __launch_bounds__(256) void k_gemm_bt(
    const unsigned short* __restrict__ A,
    const unsigned short* __restrict__ Bm,
    const float* __restrict__ bias,
    void* __restrict__ Cout,
    int M, int N, int K)
{
  __shared__ f32x4 red[4][32][64];   // 128 KB
  int m0 = blockIdx.x * 64, n0 = blockIdx.y * 128;
  int w = threadIdx.x >> 6, lane = threadIdx.x & 63;
  int c = lane & 15, klane = (lane >> 4) << 3;
  int kpw = K >> 2, kw0 = w * kpw;
  f32x4 acc[4][8];
  #pragma unroll
  for (int mf = 0; mf < 4; mf++)
    #pragma unroll
    for (int nf = 0; nf < 8; nf++) acc[mf][nf] = f32x4{0.f, 0.f, 0.f, 0.f};

  for (int kk = 0; kk < kpw; kk += 32) {
    int kb = kw0 + kk + klane;
    s16x8 a[4], b[8];
    #pragma unroll
    for (int mf = 0; mf < 4; mf++)
      a[mf] = *(const s16x8*)(A + (size_t)(m0 + mf*16 + c) * K + kb);
    #pragma unroll
    for (int nf = 0; nf < 8; nf++)
      b[nf] = *(const s16x8*)(Bm + (size_t)(n0 + nf*16 + c) * K + kb);
    #pragma unroll
    for (int mf = 0; mf < 4; mf++)
      #pragma unroll
      for (int nf = 0; nf < 8; nf++)
        acc[mf][nf] = __builtin_amdgcn_mfma_f32_16x16x32_bf16(a[mf], b[nf], acc[mf][nf], 0, 0, 0);
  }
  #pragma unroll
  for (int mf = 0; mf < 4; mf++)
    #pragma unroll
    for (int nf = 0; nf < 8; nf++)
      red[w][mf*8+nf][lane] = acc[mf][nf];
  __syncthreads();
  #pragma unroll
  for (int nf = 0; nf < 8; nf++) {
    f32x4 s = red[0][w*8+nf][lane];
    #pragma unroll
    for (int w2 = 1; w2 < 4; w2++) s += red[w2][w*8+nf][lane];
    int col = n0 + nf*16 + c;
    float bv = 0.f;
    if constexpr (ADD_BIAS) bv = bias[col];
    int rb = m0 + w*16 + ((lane >> 4) << 2);
    #pragma unroll
    for (int i = 0; i < 4; i++) {
      float val = s[i] + bv;
      if constexpr (OUT_BF16)
        ((unsigned short*)Cout)[(size_t)(rb + i) * N + col] = f2bf(val);
      else
        ((float*)Cout)[(size_t)(rb + i) * N + col] = val;
    }
  }
}

// ---------------- persistent GRU kernel ----------------
// v4: 512-thread WGs, 8 waves = 2 waves/SIMD (R0-R2 all flat at ~10.3us/step
// with 1 wave/SIMD: MfmaUtil 13 + VALU 16 + HBM 2 => ~70% of each step is
// exposed latency no single wave can hide; protocol variants didn't move it).
// Wave (kw,gg): kw in [0,4) = K-quarter (identical k/canary mapping to v3),
// gg in {0,1} = gate-group (gg0: wcomb r,z,n; gg1: whh r,z,n). Per-wave
// register state drops to wr 3x8 (96) + acc 4x3 (48), making 2-wave/SIMD
// residency feasible. gg0+gg1 waves of the same kw load the same a-frags
// (dup loads hit L1/L2).
// Reduce: gg0 wave kw keeps acc[mf==kw], writes mf!=kw to redA (9 rows);
// gg1 wave kw writes all 12 rows to redB. After B2, gg0 wave kw sums its
// owned rows across kw-partials (redA) and the whh gates (redB), does
// epilogue + publish (intra-wave tile rows). gg1 waves run ahead into the
// next step's canary+loads+MFMA while gg0 finishes the epilogue -> the two
// longest phases of adjacent steps overlap across the SIMD's 2 waves.
// Exchange protocol unchanged from v3 (optimistic + per-wave canary +
// sentinel backstop + repair store; no barrier after publish).
__global__ __launch_bounds__(512, 2) void k_gru_persist(
    const unsigned short* __restrict__ h0b,    // [B][H] bf16 initial h
    const unsigned short* __restrict__ wcomb,  // [3H][H] bf16
    const unsigned short* __restrict__ whh,    // [3H][H] bf16
    const float* __restrict__ bcomb,           // [3H]
    const float* __restrict__ bhh,             // [3H]
    const float* __restrict__ gi0,             // [B][3H] f32 (w_ih@src0+b_ih)
    const float* __restrict__ hidden0,         // [B][H] f32
    unsigned long long* __restrict__ hx64)     // [T][B][H/4] u64 view of hseq (sentinel-filled)
{
  __shared__ f32x4 redA[4][12][64];            // 48 KB (gg0 partials, 9/12 rows used)
  __shared__ f32x4 redB[4][12][64];            // 48 KB (gg1 partials)
  __shared__ unsigned long long tile64[64][4]; // 2 KB repack tile
  unsigned short* tile = (unsigned short*)tile64;

  const int wg = blockIdx.x;
  const int mg = wg & 3, p = wg >> 2;
  const int tid = threadIdx.x;
  const int wv = tid >> 6, lane = tid & 63;
  const int kw = wv & 3, gg = wv >> 2;
  const int c = lane & 15, klane = (lane >> 4) << 3, rq = (lane >> 4) << 2;
  const int u0 = p * 16, u = u0 + c, m0 = mg * 64;
  const int wk0 = kw * 256;
  const int kq = (wk0 >> 2) + ((lane >> 4) << 1);   // u64 k-offset of this lane's 16B frag
  const int cprod = 16 * kw + (lane & 15);          // canary producer for this lane

  // per-lane biases (unit u), constant across t (only gg0 uses them)
  const float bcr = bcomb[u], bcz = bcomb[HDIM + u], bcn = bcomb[2*HDIM + u];
  const float bhr = bhh[u],   bhz = bhh[HDIM + u],   bhn = bhh[2*HDIM + u];

  // weight b-frags: 3 gates for this wave's gate-group, this wave's K-quarter
  const unsigned short* Wbase = gg ? whh : wcomb;
  s16x8 wr[3][8];
  #pragma unroll
  for (int g = 0; g < 3; g++) {
    const unsigned short* Wrow = Wbase + (size_t)(g * HDIM + u0 + c) * HDIM + wk0 + klane;
    #pragma unroll
    for (int ks = 0; ks < 8; ks++)
      wr[g][ks] = *(const s16x8*)(Wrow + ks * 32);
  }

  float hcar[4];   // fp32 h carry, (r,u) fixed per thread (gg0 only)

  #pragma unroll 1
  for (int t = 0; t < TLEN; t++) {
    // ---- A-frag acquisition (per wave, its own K-quarter) ----
    s16x8 a[8][4];
    if (t == 0) {
      #pragma unroll
      for (int ks = 0; ks < 8; ks++)
        #pragma unroll
        for (int mf = 0; mf < 4; mf++)
          a[ks][mf] = *(const s16x8*)(h0b + (size_t)(m0 + mf*16 + c) * HDIM + wk0 + ks*32 + klane);
    } else {
      unsigned long long* hxp = hx64 + (size_t)(t - 1) * BDIM * (HDIM/4);
      // per-wave canary: lane l atomic-polls the LAST u64 of producer
      // cprod = 16kw + (l&15) (row m0+63, u64col 4*cprod+3). Heuristic;
      // backstop below is the correctness.
      {
        const unsigned long long* cn = hxp + (size_t)(m0 + 63) * (HDIM/4) + 4*cprod + 3;
        for (;;) {
          unsigned long long v = __hip_atomic_load(cn, __ATOMIC_RELAXED, __HIP_MEMORY_SCOPE_AGENT);
          if (__all(v != SENT64)) break;
          __builtin_amdgcn_s_sleep(1);
        }
      }
      // bulk fast path: coalesced 16B regular loads
      u64x2 va[8][4];
      #pragma unroll
      for (int ks = 0; ks < 8; ks++)
        #pragma unroll
        for (int mf = 0; mf < 4; mf++)
          va[ks][mf] = *(const u64x2*)(hxp + (size_t)(m0 + mf*16 + c) * (HDIM/4) + kq + ks*8);
      // backstop: per-u64 sentinel validation; atomic re-poll + repair
      unsigned int bad = 0;
      #pragma unroll
      for (int ks = 0; ks < 8; ks++)
        #pragma unroll
        for (int mf = 0; mf < 4; mf++)
          bad |= (unsigned int)(va[ks][mf][0] == SENT64) | (unsigned int)(va[ks][mf][1] == SENT64);
      if (__any((int)bad)) {
        #pragma unroll
        for (int ks = 0; ks < 8; ks++)
          #pragma unroll
          for (int mf = 0; mf < 4; mf++) {
            unsigned long long* pb = hxp + (size_t)(m0 + mf*16 + c) * (HDIM/4) + kq + ks*8;
            #pragma unroll
            for (int hh = 0; hh < 2; hh++) {
              if (va[ks][mf][hh] == SENT64) {
                unsigned long long v;
                do {
                  v = __hip_atomic_load(pb + hh, __ATOMIC_RELAXED, __HIP_MEMORY_SCOPE_AGENT);
                } while (v == SENT64);
                pb[hh] = v;            // repair stale local-L2 line (same value, benign)
                va[ks][mf][hh] = v;
              }
            }
          }
      }
      #pragma unroll
      for (int ks = 0; ks < 8; ks++)
        #pragma unroll
        for (int mf = 0; mf < 4; mf++)
          a[ks][mf] = __builtin_bit_cast(s16x8, va[ks][mf]);
    }

    // ---- MFMA phase: 3 gates x 4 m-frags x 8 ks = 96 MFMA ----
    f32x4 acc[4][3];
    #pragma unroll
    for (int mf = 0; mf < 4; mf++)
      #pragma unroll
      for (int g = 0; g < 3; g++) acc[mf][g] = f32x4{0.f, 0.f, 0.f, 0.f};
    #pragma unroll
    for (int ks = 0; ks < 8; ks++)
      #pragma unroll
      for (int g = 0; g < 3; g++)
        #pragma unroll
        for (int mf = 0; mf < 4; mf++)
          acc[mf][g] = __builtin_amdgcn_mfma_f32_16x16x32_bf16(a[ks][mf], wr[g][ks], acc[mf][g], 0, 0, 0);

    // ---- cross-wave K-reduce ----
    f32x4 sc[3], sh[3];
    if (gg == 0) {
      #pragma unroll
      for (int mf = 0; mf < 4; mf++) {
        if (mf != kw) {
          #pragma unroll
          for (int g = 0; g < 3; g++) redA[kw][mf*3 + g][lane] = acc[mf][g];
        } else {
          #pragma unroll
          for (int g = 0; g < 3; g++) sc[g] = acc[mf][g];
        }
      }
    } else {
      #pragma unroll
      for (int mf = 0; mf < 4; mf++)
        #pragma unroll
        for (int g = 0; g < 3; g++) redB[kw][mf*3 + g][lane] = acc[mf][g];
    }
    __syncthreads();   // B2: all partials written
    if (gg == 0) {
      #pragma unroll
      for (int k2 = 0; k2 < 4; k2++) {
        if (k2 != kw) {
          #pragma unroll
          for (int g = 0; g < 3; g++) sc[g] += redA[k2][kw*3 + g][lane];
        }
      }
      #pragma unroll
      for (int g = 0; g < 3; g++) sh[g] = redB[0][kw*3 + g][lane];
      #pragma unroll
      for (int k2 = 1; k2 < 4; k2++)
        #pragma unroll
        for (int g = 0; g < 3; g++) sh[g] += redB[k2][kw*3 + g][lane];
    }
    __syncthreads();   // B3: partials consumed -> next step's writes safe.
                       // gg1 waves now run ahead (canary+loads+MFMA of t+1)
                       // while gg0 waves do epilogue+publish of t.

    if (gg == 0) {
      // ---- epilogue: rows m0 + kw*16 + rq + i, unit u ----
      const int rbl = kw*16 + rq;
      #pragma unroll
      for (int i = 0; i < 4; i++) {
        int r = m0 + rbl + i;
        float gir, giz, gin;
        if (t == 0) {
          gir = gi0[(size_t)r * G3 + u];
          giz = gi0[(size_t)r * G3 + HDIM + u];
          gin = gi0[(size_t)r * G3 + 2*HDIM + u];
          hcar[i] = hidden0[(size_t)r * HDIM + u];
        } else {
          gir = sc[0][i] + bcr; giz = sc[1][i] + bcz; gin = sc[2][i] + bcn;
        }
        float ghr = sh[0][i] + bhr, ghz = sh[1][i] + bhz, ghn = sh[2][i] + bhn;
        float rg = 1.f / (1.f + __expf(-(gir + ghr)));
        float zg = 1.f / (1.f + __expf(-(giz + ghz)));
        float pn = gin + rg * ghn;
        pn = fminf(fmaxf(pn, -15.f), 15.f);
        float e2 = __expf(2.f * pn);
        float ng = (e2 - 1.f) / (e2 + 1.f);
        float hv = (1.f - zg) * ng + zg * hcar[i];
        hcar[i] = hv;                              // register carry
        tile[(rbl + i) * 16 + c] = f2bf(hv);       // LDS repack (intra-wave rows)
      }

      // ---- publish: wave kw publishes its own 16 tile rows (64 u64) ----
      // rows [kw*16, kw*16+16) written and read by the SAME wave ->
      // in-wave lgkmcnt ordering suffices, no barrier. Stores drain in the
      // shadow of the next step's gate+loads+MFMA.
      {
        int row = kw*16 + (lane >> 2), pq = lane & 3;
        unsigned long long v = tile64[row][pq];
        unsigned long long* dst = hx64 + (size_t)t * BDIM * (HDIM/4)
                                + (size_t)(m0 + row) * (HDIM/4) + (u0 >> 2) + pq;
        __hip_atomic_store(dst, v, __ATOMIC_RELAXED, __HIP_MEMORY_SCOPE_AGENT);
      }
    }
  }
}

// ---------------- fallback per-step GRU (only if workspace too small) ----------------
__global__ __launch_bounds__(256) void k_gru_step(
    const unsigned short* __restrict__ A1, int K1,
    const unsigned short* __restrict__ W1,
    const float* __restrict__ b1,
    const unsigned short* __restrict__ A2,
    const unsigned short* __restrict__ W2,
    const float* __restrict__ b2,
    const float* __restrict__ hprev,
    float* __restrict__ hout,
    unsigned short* __restrict__ hseq,
    int fused)
{
  __shared__ f32x4 red[4][24][64];
  int ublk = blockIdx.x & 63, mg = blockIdx.x >> 6;
  int u0 = ublk * 16, m0 = mg * 64;
  int w = threadIdx.x >> 6, lane = threadIdx.x & 63;
  int c = lane & 15, klane = (lane >> 4) << 3;
  f32x4 acc[6][4];
  #pragma unroll
  for (int g = 0; g < 6; g++)
    #pragma unroll
    for (int mf = 0; mf < 4; mf++) acc[g][mf] = f32x4{0.f, 0.f, 0.f, 0.f};

  if (fused) {
    const int kpw = HDIM >> 2;
    int kw0 = w * kpw;
    for (int kk = 0; kk < kpw; kk += 32) {
      int kb = kw0 + kk + klane;
      s16x8 a[4], bg[6];
      #pragma unroll
      for (int mf = 0; mf < 4; mf++)
        a[mf] = *(const s16x8*)(A2 + (size_t)(m0 + mf*16 + c) * HDIM + kb);
      #pragma unroll
      for (int g = 0; g < 3; g++) {
        bg[g]   = *(const s16x8*)(W1 + (size_t)(g*HDIM + u0 + c) * HDIM + kb);
        bg[g+3] = *(const s16x8*)(W2 + (size_t)(g*HDIM + u0 + c) * HDIM + kb);
      }
      #pragma unroll
      for (int g = 0; g < 6; g++)
        #pragma unroll
        for (int mf = 0; mf < 4; mf++)
          acc[g][mf] = __builtin_amdgcn_mfma_f32_16x16x32_bf16(a[mf], bg[g], acc[g][mf], 0, 0, 0);
    }
  } else {
    {
      int kpw = K1 >> 2, kw0 = w * kpw;
      for (int kk = 0; kk < kpw; kk += 32) {
        int kb = kw0 + kk + klane;
        s16x8 a[4], bg[3];
        #pragma unroll
        for (int mf = 0; mf < 4; mf++)
          a[mf] = *(const s16x8*)(A1 + (size_t)(m0 + mf*16 + c) * K1 + kb);
        #pragma unroll
        for (int g = 0; g < 3; g++)
          bg[g] = *(const s16x8*)(W1 + (size_t)(g*HDIM + u0 + c) * K1 + kb);
        #pragma unroll
        for (int g = 0; g < 3; g++)
          #pragma unroll
          for (int mf = 0; mf < 4; mf++)
            acc[g][mf] = __builtin_amdgcn_mfma_f32_16x16x32_bf16(a[mf], bg[g], acc[g][mf], 0, 0, 0);
      }
    }
    {
      int kpw = HDIM >> 2, kw0 = w * kpw;
      for (int kk = 0; kk < kpw; kk += 32) {
        int kb = kw0 + kk + klane;
        s16x8 a[4], bg[3];
        #pragma unroll
        for (int mf = 0; mf < 4; mf++)
          a[mf] = *(const s16x8*)(A2 + (size_t)(m0 + mf*16 + c) * HDIM + kb);
        #pragma unroll
        for (int g = 0; g < 3; g++)
          bg[g] = *(const s16x8*)(W2 + (size_t)(g*HDIM + u0 + c) * HDIM + kb);
        #pragma unroll
        for (int g = 0; g < 3; g++)
          #pragma unroll
          for (int mf = 0; mf < 4; mf++)
            acc[g+3][mf] = __builtin_amdgcn_mfma_f32_16x16x32_bf16(a[mf], bg[g], acc[g+3][mf], 0, 0, 0);
      }
    }
  }

  #pragma unroll
  for (int g = 0; g < 6; g++)
    #pragma unroll
    for (int mf = 0; mf < 4; mf++)
      red[w][g*4+mf][lane] = acc[g][mf];
  __syncthreads();

  f32x4 gg[6];
  #pragma unroll
  for (int g = 0; g < 6; g++) {
    f32x4 sum = red[0][g*4+w][lane];
    #pragma unroll
    for (int w2 = 1; w2 < 4; w2++) sum += red[w2][g*4+w][lane];
    gg[g] = sum;
  }
  int u = u0 + c;
  float b1r = b1[u], b1z = b1[HDIM+u], b1n = b1[2*HDIM+u];
  float b2r = b2[u], b2z = b2[HDIM+u], b2n = b2[2*HDIM+u];
  int rb = m0 + w*16 + ((lane >> 4) << 2);
  #pragma unroll
  for (int i = 0; i < 4; i++) {
    float pre_r = gg[0][i] + b1r + gg[3][i] + b2r;
    float pre_z = gg[1][i] + b1z + gg[4][i] + b2z;
    float ghn  = gg[5][i] + b2n;
    float r = 1.f / (1.f + __expf(-pre_r));
    float z = 1.f / (1.f + __expf(-pre_z));
    float pn = gg[2][i] + b1n + r * ghn;
    pn = fminf(fmaxf(pn, -15.f), 15.f);
    float e2 = __expf(2.f * pn);
    float n = (e2 - 1.f) / (e2 + 1.f);
    size_t idx = (size_t)(rb + i) * HDIM + u;
    float hp = hprev[idx];
    float hn = (1.f - z) * n + z * hp;
    hout[idx] = hn;
    hseq[idx] = f2bf(hn);
  }
}

// ---------------- host ----------------

extern "C" void kernel_launch(void* const* d_in, const int* in_sizes, int n_in,
                              void* d_out, int out_size, void* d_ws, size_t ws_size,
                              hipStream_t stream) {
  const float* src    = (const float*)d_in[0];
  const float* hidden = (const float*)d_in[2];
  const float* w_ih   = (const float*)d_in[3];
  const float* w_hh   = (const float*)d_in[4];
  const float* b_ih   = (const float*)d_in[5];
  const float* b_hh   = (const float*)d_in[6];
  const float* w_fc   = (const float*)d_in[7];
  const float* b_fc   = (const float*)d_in[8];
  float* out = (float*)d_out;

  uint8_t* ws = (uint8_t*)d_ws;
  size_t off = 0;
  auto alloc = [&](size_t bytes) -> void* {
    void* pp = ws + off;
    off += (bytes + 255) & ~(size_t)255;
    return pp;
  };
  unsigned short* wih_b  = (unsigned short*)alloc((size_t)G3*ODIM*2);
  unsigned short* whh_b  = (unsigned short*)alloc((size_t)G3*HDIM*2);
  unsigned short* wfc_b  = (unsigned short*)alloc((size_t)ODIM*HDIM*2);
  unsigned short* wfcT_b = (unsigned short*)alloc((size_t)HDIM*ODIM*2);
  unsigned short* wcomb  = (unsigned short*)alloc((size_t)G3*HDIM*2);
  unsigned short* src0_b = (unsigned short*)alloc((size_t)BDIM*ODIM*2);
  unsigned short* h0_b   = (unsigned short*)alloc((size_t)BDIM*HDIM*2);
  float* bcomb = (float*)alloc((size_t)G3*4);
  float* hbuf0 = (float*)alloc((size_t)BDIM*HDIM*4);
  float* hbuf1 = (float*)alloc((size_t)BDIM*HDIM*4);
  unsigned short* hpp = (unsigned short*)alloc((size_t)2*BDIM*HDIM*2);
  unsigned short* hseq = (unsigned short*)alloc((size_t)TLEN*BDIM*HDIM*2);
  float* gi0 = (float*)alloc((size_t)BDIM*G3*4);
  bool big = (off <= ws_size);   // persistent path needs everything

  // prep
  k_f32_to_bf16<<<G3*ODIM/4/256, 256, 0, stream>>>(w_ih, wih_b, G3*ODIM/4);
  k_f32_to_bf16<<<G3*HDIM/4/256, 256, 0, stream>>>(w_hh, whh_b, G3*HDIM/4);
  k_f32_to_bf16<<<ODIM*HDIM/4/256, 256, 0, stream>>>(w_fc, wfc_b, ODIM*HDIM/4);
  k_f32_to_bf16<<<BDIM*ODIM/4/256, 256, 0, stream>>>(src, src0_b, BDIM*ODIM/4);
  k_f32_to_bf16<<<BDIM*HDIM/4/256, 256, 0, stream>>>(hidden, h0_b, BDIM*HDIM/4);
  k_transpose_f32_bf16<<<dim3(HDIM/32, ODIM/32), dim3(32, 8), 0, stream>>>(w_fc, wfcT_b, ODIM, HDIM);
  k_gemm_bt<true, false><<<dim3(G3/64, HDIM/128), 256, 0, stream>>>(wih_b, wfcT_b, nullptr, wcomb, G3, HDIM, ODIM);
  k_bcomb<<<G3/4, 256, 0, stream>>>(w_ih, b_ih, b_fc, bcomb);

  if (big) {
    // sentinel-fill the exchange buffer (REQUIRED every call: harness does
    // not re-poison between replays; protocol self-syncs on 0xFF)
    hipMemsetAsync(hseq, 0xFF, (size_t)TLEN*BDIM*HDIM*2, stream);
    // gi0 = src0 @ w_ih^T + b_ih  (f32, exact input for step 0)
    k_gemm_bt<false, true><<<dim3(BDIM/64, G3/128), 256, 0, stream>>>(
        src0_b, wih_b, b_ih, gi0, BDIM, G3, ODIM);
    k_gru_persist<<<256, 512, 0, stream>>>(h0_b, wcomb, whh_b, bcomb, b_hh,
                                           gi0, hidden,
                                           (unsigned long long*)hseq);
    // batched output GEMM: Y[T*B][O] = Hseq[T*B][H] @ w_fc^T + b_fc
    k_gemm_bt<false, true><<<dim3(TLEN*BDIM/64, ODIM/128), 256, 0, stream>>>(
        hseq, wfc_b, b_fc, out, TLEN*BDIM, ODIM, HDIM);
  } else {
    for (int t = 0; t < TLEN; t++) {
      const unsigned short* aprev = (t == 0) ? h0_b : hpp + (size_t)((t-1)&1)*BDIM*HDIM;
      unsigned short* hs_cur = hpp + (size_t)(t&1)*BDIM*HDIM;
      const float* hprev_f = (t == 0) ? hidden : ((t & 1) ? hbuf0 : hbuf1);
      float* hout_f = (t & 1) ? hbuf1 : hbuf0;
      if (t == 0) {
        k_gru_step<<<256, 256, 0, stream>>>(src0_b, ODIM, wih_b, b_ih,
            aprev, whh_b, b_hh, hprev_f, hout_f, hs_cur, 0);
      } else {
        k_gru_step<<<256, 256, 0, stream>>>(aprev, HDIM, wcomb, bcomb,
            aprev, whh_b, b_hh, hprev_f, hout_f, hs_cur, 1);
      }
      k_gemm_bt<false, true><<<dim3(BDIM/64, ODIM/128), 256, 0, stream>>>(
          hs_cur, wfc_b, b_fc, out + (size_t)t*BDIM*ODIM, BDIM, ODIM, HDIM);
    }
  }
}

// Round 4
// 2208.986 us; speedup vs baseline: 2.0605x; 2.0605x over previous
//
#include <hip/hip_runtime.h>
#include <stdint.h>

#define HDIM 1024
#define ODIM 768
#define BDIM 256
#define TLEN 256
#define G3 (3*HDIM)

typedef __attribute__((ext_vector_type(4))) float f32x4;
typedef __attribute__((ext_vector_type(8))) short s16x8;
typedef __attribute__((ext_vector_type(2))) unsigned long long u64x2;

#define SENT64 0xFFFFFFFFFFFFFFFFull

static __device__ __forceinline__ unsigned short f2bf(float f) {
  uint32_t u = __builtin_bit_cast(uint32_t, f);
  return (unsigned short)((u + 0x7fffu + ((u >> 16) & 1u)) >> 16);
}

// ---------------- prep kernels ----------------

__global__ void k_f32_to_bf16(const float* __restrict__ in, unsigned short* __restrict__ out, int n4) {
  int i = blockIdx.x * 256 + threadIdx.x;
  if (i >= n4) return;
  float4 v = ((const float4*)in)[i];
  ushort4 o;
  o.x = f2bf(v.x); o.y = f2bf(v.y); o.z = f2bf(v.z); o.w = f2bf(v.w);
  ((ushort4*)out)[i] = o;
}

// in [R][C] f32 -> out [C][R] bf16
__global__ void k_transpose_f32_bf16(const float* __restrict__ in, unsigned short* __restrict__ out, int R, int C) {
  __shared__ float tile[32][33];
  int c0 = blockIdx.x * 32, r0 = blockIdx.y * 32;
  int tx = threadIdx.x, ty = threadIdx.y;
  #pragma unroll
  for (int i = 0; i < 32; i += 8)
    tile[ty + i][tx] = in[(size_t)(r0 + ty + i) * C + (c0 + tx)];
  __syncthreads();
  #pragma unroll
  for (int i = 0; i < 32; i += 8)
    out[(size_t)(c0 + ty + i) * R + (r0 + tx)] = f2bf(tile[tx][ty + i]);
}

// b_comb[c] = b_ih[c] + sum_o w_ih[c][o] * b_fc[o]   (fp32)
__global__ void k_bcomb(const float* __restrict__ w_ih, const float* __restrict__ b_ih,
                        const float* __restrict__ b_fc, float* __restrict__ bc) {
  int gw = (blockIdx.x * 256 + threadIdx.x) >> 6;
  int lane = threadIdx.x & 63;
  if (gw >= G3) return;
  const float* row = w_ih + (size_t)gw * ODIM;
  float s = 0.f;
  for (int o = lane; o < ODIM; o += 64) s += row[o] * b_fc[o];
  #pragma unroll
  for (int off = 32; off; off >>= 1) s += __shfl_down(s, off);
  if (lane == 0) bc[gw] = s + b_ih[gw];
}

// ---------------- generic bf16 GEMM: C[M][N] = A[M][K] * Bm[N][K]^T (+bias) ----------------
template<bool OUT_BF16, bool ADD_BIAS>
__global__ __launch_bounds__(256) void k_gemm_bt(
    const unsigned short* __restrict__ A,
    const unsigned short* __restrict__ Bm,
    const float* __restrict__ bias,
    void* __restrict__ Cout,
    int M, int N, int K)
{
  __shared__ f32x4 red[4][32][64];   // 128 KB
  int m0 = blockIdx.x * 64, n0 = blockIdx.y * 128;
  int w = threadIdx.x >> 6, lane = threadIdx.x & 63;
  int c = lane & 15, klane = (lane >> 4) << 3;
  int kpw = K >> 2, kw0 = w * kpw;
  f32x4 acc[4][8];
  #pragma unroll
  for (int mf = 0; mf < 4; mf++)
    #pragma unroll
    for (int nf = 0; nf < 8; nf++) acc[mf][nf] = f32x4{0.f, 0.f, 0.f, 0.f};

  for (int kk = 0; kk < kpw; kk += 32) {
    int kb = kw0 + kk + klane;
    s16x8 a[4], b[8];
    #pragma unroll
    for (int mf = 0; mf < 4; mf++)
      a[mf] = *(const s16x8*)(A + (size_t)(m0 + mf*16 + c) * K + kb);
    #pragma unroll
    for (int nf = 0; nf < 8; nf++)
      b[nf] = *(const s16x8*)(Bm + (size_t)(n0 + nf*16 + c) * K + kb);
    #pragma unroll
    for (int mf = 0; mf < 4; mf++)
      #pragma unroll
      for (int nf = 0; nf < 8; nf++)
        acc[mf][nf] = __builtin_amdgcn_mfma_f32_16x16x32_bf16(a[mf], b[nf], acc[mf][nf], 0, 0, 0);
  }
  #pragma unroll
  for (int mf = 0; mf < 4; mf++)
    #pragma unroll
    for (int nf = 0; nf < 8; nf++)
      red[w][mf*8+nf][lane] = acc[mf][nf];
  __syncthreads();
  #pragma unroll
  for (int nf = 0; nf < 8; nf++) {
    f32x4 s = red[0][w*8+nf][lane];
    #pragma unroll
    for (int w2 = 1; w2 < 4; w2++) s += red[w2][w*8+nf][lane];
    int col = n0 + nf*16 + c;
    float bv = 0.f;
    if constexpr (ADD_BIAS) bv = bias[col];
    int rb = m0 + w*16 + ((lane >> 4) << 2);
    #pragma unroll
    for (int i = 0; i < 4; i++) {
      float val = s[i] + bv;
      if constexpr (OUT_BF16)
        ((unsigned short*)Cout)[(size_t)(rb + i) * N + col] = f2bf(val);
      else
        ((float*)Cout)[(size_t)(rb + i) * N + col] = val;
    }
  }
}

// ---------------- output GEMM over block-layout hseq ----------------
// A is hseq in BLOCK layout: u64 index = ((t*64 + p')*4 + mg)*256 + rowl*4 + q
// where logical A row r = t*256 + mg*64 + rowl, logical k-cols [16p'+4q ..+4).
// Identical MFMA structure to k_gemm_bt<false,true>; only A addressing differs.
__global__ __launch_bounds__(256) void k_gemm_hseq(
    const unsigned long long* __restrict__ Ahx,  // block-layout hseq
    const unsigned short* __restrict__ Bm,       // [N][K] bf16 (w_fc)
    const float* __restrict__ bias,
    float* __restrict__ Cout)
{
  const int M = TLEN*BDIM, N = ODIM, K = HDIM;
  __shared__ f32x4 red[4][32][64];   // 128 KB
  int m0 = blockIdx.x * 64, n0 = blockIdx.y * 128;
  int w = threadIdx.x >> 6, lane = threadIdx.x & 63;
  int c = lane & 15, klane = (lane >> 4) << 3;
  int kpw = K >> 2, kw0 = w * kpw;
  const int tb = m0 >> 8, mgb = (m0 >> 6) & 3;   // m0 is 64-aligned: block-constant
  f32x4 acc[4][8];
  #pragma unroll
  for (int mf = 0; mf < 4; mf++)
    #pragma unroll
    for (int nf = 0; nf < 8; nf++) acc[mf][nf] = f32x4{0.f, 0.f, 0.f, 0.f};

  for (int kk = 0; kk < kpw; kk += 32) {
    int kb = kw0 + kk + klane;
    int uk = kb >> 2;                 // u64 col index; even (klane mult of 8)
    s16x8 a[4], b[8];
    #pragma unroll
    for (int mf = 0; mf < 4; mf++)
      a[mf] = *(const s16x8*)(Ahx + (((size_t)((tb*64 + (uk>>2))*4 + mgb)) << 8)
                                   + (size_t)(mf*16 + c)*4 + (uk & 3));
    #pragma unroll
    for (int nf = 0; nf < 8; nf++)
      b[nf] = *(const s16x8*)(Bm + (size_t)(n0 + nf*16 + c) * K + kb);
    #pragma unroll
    for (int mf = 0; mf < 4; mf++)
      #pragma unroll
      for (int nf = 0; nf < 8; nf++)
        acc[mf][nf] = __builtin_amdgcn_mfma_f32_16x16x32_bf16(a[mf], b[nf], acc[mf][nf], 0, 0, 0);
  }
  #pragma unroll
  for (int mf = 0; mf < 4; mf++)
    #pragma unroll
    for (int nf = 0; nf < 8; nf++)
      red[w][mf*8+nf][lane] = acc[mf][nf];
  __syncthreads();
  #pragma unroll
  for (int nf = 0; nf < 8; nf++) {
    f32x4 s = red[0][w*8+nf][lane];
    #pragma unroll
    for (int w2 = 1; w2 < 4; w2++) s += red[w2][w*8+nf][lane];
    int col = n0 + nf*16 + c;
    float bv = bias[col];
    int rb = m0 + w*16 + ((lane >> 4) << 2);
    #pragma unroll
    for (int i = 0; i < 4; i++)
      Cout[(size_t)(rb + i) * N + col] = s[i] + bv;
  }
}

// ---------------- persistent GRU kernel ----------------
// v5 = R2 structure (best measured: ~10.3us/step) + BLOCK-CONTIGUOUS exchange
// layout. R3 post-mortem: 2-waves/SIMD is structurally impossible (live set
// ~290 regs > 128 cap -> scratch spills exploded FETCH 19x). 1 wave/SIMD is
// forced; remaining lever is the MALL transaction geometry.
// OLD layout: each WG published 64 scattered 32B chunks (row-strided) =
// 256 partial-line 8B agent atomics -> MALL read-modify-writes every 64B
// line. NEW layout: hseq u64 index = ((t*64+p)*4+mg)*256 + rowl*4 + q ->
// each (WG,t) publishes ONE contiguous 2KB block (32 full 64B lines, no
// RMW); canary = last u64 of the block; consumer bulk loads remain
// coalesced (each half-wave reads a contiguous 512B chunk per (ks,mf)).
// Protocol unchanged from R2: optimistic bulk loads gated by per-wave
// canary; per-u64 sentinel validation; atomic re-poll + repair store
// backstop; B2/B3 around the LDS reduce; no barrier after publish.
__global__ __launch_bounds__(256, 1) void k_gru_persist(
    const unsigned short* __restrict__ h0b,    // [B][H] bf16 initial h
    const unsigned short* __restrict__ wcomb,  // [3H][H] bf16
    const unsigned short* __restrict__ whh,    // [3H][H] bf16
    const float* __restrict__ bcomb,           // [3H]
    const float* __restrict__ bhh,             // [3H]
    const float* __restrict__ gi0,             // [B][3H] f32 (w_ih@src0+b_ih)
    const float* __restrict__ hidden0,         // [B][H] f32
    unsigned long long* __restrict__ hx64)     // [T*64*4*256] u64 block-layout hseq (sentinel-filled)
{
  __shared__ f32x4 red[4][24][64];            // 96 KB
  __shared__ unsigned long long tile64[64][4]; // 2 KB repack tile
  unsigned short* tile = (unsigned short*)tile64;

  const int wg = blockIdx.x;
  const int mg = wg & 3, p = wg >> 2;
  const int tid = threadIdx.x;
  const int w = tid >> 6, lane = tid & 63;
  const int c = lane & 15, klane = (lane >> 4) << 3, rq = (lane >> 4) << 2;
  const int u0 = p * 16, u = u0 + c, m0 = mg * 64;
  const int wk0 = w * 256;
  const int rp = lane >> 5;                    // p' sub-offset within a ks pair (0/1)
  const int q0 = ((lane >> 4) & 1) << 1;       // u64 q within block (0/2)
  const int cprod = 16 * w + (lane & 15);      // canary producer for this lane

  // per-lane biases (unit u), constant across t
  const float bcr = bcomb[u], bcz = bcomb[HDIM + u], bcn = bcomb[2*HDIM + u];
  const float bhr = bhh[u],   bhz = bhh[HDIM + u],   bhn = bhh[2*HDIM + u];

  // load weight b-frags into registers: wr[gate][kstep]  (192 regs, AV file)
  s16x8 wr[6][8];
  #pragma unroll
  for (int g = 0; g < 6; g++) {
    const unsigned short* W = (g < 3) ? (wcomb + (size_t)g * HDIM * HDIM)
                                      : (whh   + (size_t)(g - 3) * HDIM * HDIM);
    const unsigned short* Wrow = W + (size_t)(u0 + c) * HDIM + wk0 + klane;
    #pragma unroll
    for (int ks = 0; ks < 8; ks++)
      wr[g][ks] = *(const s16x8*)(Wrow + ks * 32);
  }

  float hcar[4];   // fp32 h carry, (r,u) fixed per thread

  #pragma unroll 1
  for (int t = 0; t < TLEN; t++) {
    // ---- A-frag acquisition ----
    s16x8 a[8][4];
    if (t == 0) {
      #pragma unroll
      for (int ks = 0; ks < 8; ks++)
        #pragma unroll
        for (int mf = 0; mf < 4; mf++)
          a[ks][mf] = *(const s16x8*)(h0b + (size_t)(m0 + mf*16 + c) * HDIM + wk0 + ks*32 + klane);
    } else {
      unsigned long long* hxp = hx64 + (size_t)(t - 1) * (64*4*256);
      // per-wave canary: lane l atomic-polls the LAST u64 of producer
      // block (cprod = 16w + (l&15), mg). Heuristic gate; backstop below
      // is the correctness.
      {
        const unsigned long long* cn = hxp + (((size_t)(cprod*4 + mg)) << 8) + 255;
        for (;;) {
          unsigned long long v = __hip_atomic_load(cn, __ATOMIC_RELAXED, __HIP_MEMORY_SCOPE_AGENT);
          if (__all(v != SENT64)) break;
          __builtin_amdgcn_s_sleep(1);
        }
      }
      // bulk fast path: coalesced 16B regular loads. For (ks,mf) a half-wave
      // reads a contiguous 512B span of producer block (16w+2ks+rp, mg).
      u64x2 va[8][4];
      #pragma unroll
      for (int ks = 0; ks < 8; ks++)
        #pragma unroll
        for (int mf = 0; mf < 4; mf++)
          va[ks][mf] = *(const u64x2*)(hxp + (((size_t)((16*w + 2*ks + rp)*4 + mg)) << 8)
                                            + (size_t)(mf*16 + c)*4 + q0);
      // backstop: per-u64 sentinel validation; atomic re-poll + repair
      unsigned int bad = 0;
      #pragma unroll
      for (int ks = 0; ks < 8; ks++)
        #pragma unroll
        for (int mf = 0; mf < 4; mf++)
          bad |= (unsigned int)(va[ks][mf][0] == SENT64) | (unsigned int)(va[ks][mf][1] == SENT64);
      if (__any((int)bad)) {
        #pragma unroll
        for (int ks = 0; ks < 8; ks++)
          #pragma unroll
          for (int mf = 0; mf < 4; mf++) {
            unsigned long long* pb = hxp + (((size_t)((16*w + 2*ks + rp)*4 + mg)) << 8)
                                         + (size_t)(mf*16 + c)*4 + q0;
            #pragma unroll
            for (int hh = 0; hh < 2; hh++) {
              if (va[ks][mf][hh] == SENT64) {
                unsigned long long v;
                do {
                  v = __hip_atomic_load(pb + hh, __ATOMIC_RELAXED, __HIP_MEMORY_SCOPE_AGENT);
                } while (v == SENT64);
                pb[hh] = v;            // repair stale local-L2 line (same value, benign)
                va[ks][mf][hh] = v;
              }
            }
          }
      }
      #pragma unroll
      for (int ks = 0; ks < 8; ks++)
        #pragma unroll
        for (int mf = 0; mf < 4; mf++)
          a[ks][mf] = __builtin_bit_cast(s16x8, va[ks][mf]);
    }

    // ---- MFMA phase ----
    f32x4 acc[4][6];
    #pragma unroll
    for (int mf = 0; mf < 4; mf++)
      #pragma unroll
      for (int g = 0; g < 6; g++) acc[mf][g] = f32x4{0.f, 0.f, 0.f, 0.f};
    #pragma unroll
    for (int ks = 0; ks < 8; ks++)
      #pragma unroll
      for (int g = 0; g < 6; g++)
        #pragma unroll
        for (int mf = 0; mf < 4; mf++)
          acc[mf][g] = __builtin_amdgcn_mfma_f32_16x16x32_bf16(a[ks][mf], wr[g][ks], acc[mf][g], 0, 0, 0);

    // ---- cross-wave K-reduce: wave w keeps m-frag mf==w ----
    #pragma unroll
    for (int mf = 0; mf < 4; mf++) {
      if (mf != w) {
        #pragma unroll
        for (int g = 0; g < 6; g++) red[w][mf*6 + g][lane] = acc[mf][g];
      }
    }
    f32x4 s[6];
    #pragma unroll
    for (int mf = 0; mf < 4; mf++) {
      if (mf == w) {
        #pragma unroll
        for (int g = 0; g < 6; g++) s[g] = acc[mf][g];
      }
    }
    __syncthreads();   // B2: red writes complete
    #pragma unroll
    for (int w2 = 0; w2 < 4; w2++) {
      if (w2 != w) {
        #pragma unroll
        for (int g = 0; g < 6; g++) s[g] += red[w2][w*6 + g][lane];
      }
    }
    __syncthreads();   // B3: red consumed -> next step's writes are safe.
                       // (Before publish, so no barrier waits on publish vmcnt.)

    // ---- epilogue: rows m0 + w*16 + rq + i, unit u ----
    const int rbl = w*16 + rq;   // row within the 64-row block
    #pragma unroll
    for (int i = 0; i < 4; i++) {
      int r = m0 + rbl + i;
      float gir, giz, gin;
      if (t == 0) {
        gir = gi0[(size_t)r * G3 + u];
        giz = gi0[(size_t)r * G3 + HDIM + u];
        gin = gi0[(size_t)r * G3 + 2*HDIM + u];
        hcar[i] = hidden0[(size_t)r * HDIM + u];
      } else {
        gir = s[0][i] + bcr; giz = s[1][i] + bcz; gin = s[2][i] + bcn;
      }
      float ghr = s[3][i] + bhr, ghz = s[4][i] + bhz, ghn = s[5][i] + bhn;
      float rg = 1.f / (1.f + __expf(-(gir + ghr)));
      float zg = 1.f / (1.f + __expf(-(giz + ghz)));
      float pn = gin + rg * ghn;
      pn = fminf(fmaxf(pn, -15.f), 15.f);
      float e2 = __expf(2.f * pn);
      float ng = (e2 - 1.f) / (e2 + 1.f);
      float hv = (1.f - zg) * ng + zg * hcar[i];
      hcar[i] = hv;                              // register carry
      tile[(rbl + i) * 16 + c] = f2bf(hv);       // LDS repack (intra-wave rows)
    }

    // ---- publish: one contiguous 2KB block per (WG,t) ----
    // thread tid stores u64 #tid of the block -> 32 FULL 64B lines, no
    // partial-line RMW at the MALL. tile rows [w*16,w*16+16) were written
    // by the same wave (in-wave lgkmcnt ordering suffices, no barrier).
    {
      unsigned long long v = tile64[tid >> 2][tid & 3];
      unsigned long long* dst = hx64 + (size_t)t * (64*4*256)
                              + (((size_t)(p*4 + mg)) << 8) + tid;
      __hip_atomic_store(dst, v, __ATOMIC_RELAXED, __HIP_MEMORY_SCOPE_AGENT);
    }
  }
}

// ---------------- fallback per-step GRU (only if workspace too small) ----------------
__global__ __launch_bounds__(256) void k_gru_step(
    const unsigned short* __restrict__ A1, int K1,
    const unsigned short* __restrict__ W1,
    const float* __restrict__ b1,
    const unsigned short* __restrict__ A2,
    const unsigned short* __restrict__ W2,
    const float* __restrict__ b2,
    const float* __restrict__ hprev,
    float* __restrict__ hout,
    unsigned short* __restrict__ hseq,
    int fused)
{
  __shared__ f32x4 red[4][24][64];
  int ublk = blockIdx.x & 63, mg = blockIdx.x >> 6;
  int u0 = ublk * 16, m0 = mg * 64;
  int w = threadIdx.x >> 6, lane = threadIdx.x & 63;
  int c = lane & 15, klane = (lane >> 4) << 3;
  f32x4 acc[6][4];
  #pragma unroll
  for (int g = 0; g < 6; g++)
    #pragma unroll
    for (int mf = 0; mf < 4; mf++) acc[g][mf] = f32x4{0.f, 0.f, 0.f, 0.f};

  if (fused) {
    const int kpw = HDIM >> 2;
    int kw0 = w * kpw;
    for (int kk = 0; kk < kpw; kk += 32) {
      int kb = kw0 + kk + klane;
      s16x8 a[4], bg[6];
      #pragma unroll
      for (int mf = 0; mf < 4; mf++)
        a[mf] = *(const s16x8*)(A2 + (size_t)(m0 + mf*16 + c) * HDIM + kb);
      #pragma unroll
      for (int g = 0; g < 3; g++) {
        bg[g]   = *(const s16x8*)(W1 + (size_t)(g*HDIM + u0 + c) * HDIM + kb);
        bg[g+3] = *(const s16x8*)(W2 + (size_t)(g*HDIM + u0 + c) * HDIM + kb);
      }
      #pragma unroll
      for (int g = 0; g < 6; g++)
        #pragma unroll
        for (int mf = 0; mf < 4; mf++)
          acc[g][mf] = __builtin_amdgcn_mfma_f32_16x16x32_bf16(a[mf], bg[g], acc[g][mf], 0, 0, 0);
    }
  } else {
    {
      int kpw = K1 >> 2, kw0 = w * kpw;
      for (int kk = 0; kk < kpw; kk += 32) {
        int kb = kw0 + kk + klane;
        s16x8 a[4], bg[3];
        #pragma unroll
        for (int mf = 0; mf < 4; mf++)
          a[mf] = *(const s16x8*)(A1 + (size_t)(m0 + mf*16 + c) * K1 + kb);
        #pragma unroll
        for (int g = 0; g < 3; g++)
          bg[g] = *(const s16x8*)(W1 + (size_t)(g*HDIM + u0 + c) * K1 + kb);
        #pragma unroll
        for (int g = 0; g < 3; g++)
          #pragma unroll
          for (int mf = 0; mf < 4; mf++)
            acc[g][mf] = __builtin_amdgcn_mfma_f32_16x16x32_bf16(a[mf], bg[g], acc[g][mf], 0, 0, 0);
      }
    }
    {
      int kpw = HDIM >> 2, kw0 = w * kpw;
      for (int kk = 0; kk < kpw; kk += 32) {
        int kb = kw0 + kk + klane;
        s16x8 a[4], bg[3];
        #pragma unroll
        for (int mf = 0; mf < 4; mf++)
          a[mf] = *(const s16x8*)(A2 + (size_t)(m0 + mf*16 + c) * HDIM + kb);
        #pragma unroll
        for (int g = 0; g < 3; g++)
          bg[g] = *(const s16x8*)(W2 + (size_t)(g*HDIM + u0 + c) * HDIM + kb);
        #pragma unroll
        for (int g = 0; g < 3; g++)
          #pragma unroll
          for (int mf = 0; mf < 4; mf++)
            acc[g+3][mf] = __builtin_amdgcn_mfma_f32_16x16x32_bf16(a[mf], bg[g], acc[g+3][mf], 0, 0, 0);
      }
    }
  }

  #pragma unroll
  for (int g = 0; g < 6; g++)
    #pragma unroll
    for (int mf = 0; mf < 4; mf++)
      red[w][g*4+mf][lane] = acc[g][mf];
  __syncthreads();

  f32x4 gg[6];
  #pragma unroll
  for (int g = 0; g < 6; g++) {
    f32x4 sum = red[0][g*4+w][lane];
    #pragma unroll
    for (int w2 = 1; w2 < 4; w2++) sum += red[w2][g*4+w][lane];
    gg[g] = sum;
  }
  int u = u0 + c;
  float b1r = b1[u], b1z = b1[HDIM+u], b1n = b1[2*HDIM+u];
  float b2r = b2[u], b2z = b2[HDIM+u], b2n = b2[2*HDIM+u];
  int rb = m0 + w*16 + ((lane >> 4) << 2);
  #pragma unroll
  for (int i = 0; i < 4; i++) {
    float pre_r = gg[0][i] + b1r + gg[3][i] + b2r;
    float pre_z = gg[1][i] + b1z + gg[4][i] + b2z;
    float ghn  = gg[5][i] + b2n;
    float r = 1.f / (1.f + __expf(-pre_r));
    float z = 1.f / (1.f + __expf(-pre_z));
    float pn = gg[2][i] + b1n + r * ghn;
    pn = fminf(fmaxf(pn, -15.f), 15.f);
    float e2 = __expf(2.f * pn);
    float n = (e2 - 1.f) / (e2 + 1.f);
    size_t idx = (size_t)(rb + i) * HDIM + u;
    float hp = hprev[idx];
    float hn = (1.f - z) * n + z * hp;
    hout[idx] = hn;
    hseq[idx] = f2bf(hn);
  }
}

// ---------------- host ----------------

extern "C" void kernel_launch(void* const* d_in, const int* in_sizes, int n_in,
                              void* d_out, int out_size, void* d_ws, size_t ws_size,
                              hipStream_t stream) {
  const float* src    = (const float*)d_in[0];
  const float* hidden = (const float*)d_in[2];
  const float* w_ih   = (const float*)d_in[3];
  const float* w_hh   = (const float*)d_in[4];
  const float* b_ih   = (const float*)d_in[5];
  const float* b_hh   = (const float*)d_in[6];
  const float* w_fc   = (const float*)d_in[7];
  const float* b_fc   = (const float*)d_in[8];
  float* out = (float*)d_out;

  uint8_t* ws = (uint8_t*)d_ws;
  size_t off = 0;
  auto alloc = [&](size_t bytes) -> void* {
    void* pp = ws + off;
    off += (bytes + 255) & ~(size_t)255;
    return pp;
  };
  unsigned short* wih_b  = (unsigned short*)alloc((size_t)G3*ODIM*2);
  unsigned short* whh_b  = (unsigned short*)alloc((size_t)G3*HDIM*2);
  unsigned short* wfc_b  = (unsigned short*)alloc((size_t)ODIM*HDIM*2);
  unsigned short* wfcT_b = (unsigned short*)alloc((size_t)HDIM*ODIM*2);
  unsigned short* wcomb  = (unsigned short*)alloc((size_t)G3*HDIM*2);
  unsigned short* src0_b = (unsigned short*)alloc((size_t)BDIM*ODIM*2);
  unsigned short* h0_b   = (unsigned short*)alloc((size_t)BDIM*HDIM*2);
  float* bcomb = (float*)alloc((size_t)G3*4);
  float* hbuf0 = (float*)alloc((size_t)BDIM*HDIM*4);
  float* hbuf1 = (float*)alloc((size_t)BDIM*HDIM*4);
  unsigned short* hpp = (unsigned short*)alloc((size_t)2*BDIM*HDIM*2);
  unsigned short* hseq = (unsigned short*)alloc((size_t)TLEN*BDIM*HDIM*2);
  float* gi0 = (float*)alloc((size_t)BDIM*G3*4);
  bool big = (off <= ws_size);   // persistent path needs everything

  // prep
  k_f32_to_bf16<<<G3*ODIM/4/256, 256, 0, stream>>>(w_ih, wih_b, G3*ODIM/4);
  k_f32_to_bf16<<<G3*HDIM/4/256, 256, 0, stream>>>(w_hh, whh_b, G3*HDIM/4);
  k_f32_to_bf16<<<ODIM*HDIM/4/256, 256, 0, stream>>>(w_fc, wfc_b, ODIM*HDIM/4);
  k_f32_to_bf16<<<BDIM*ODIM/4/256, 256, 0, stream>>>(src, src0_b, BDIM*ODIM/4);
  k_f32_to_bf16<<<BDIM*HDIM/4/256, 256, 0, stream>>>(hidden, h0_b, BDIM*HDIM/4);
  k_transpose_f32_bf16<<<dim3(HDIM/32, ODIM/32), dim3(32, 8), 0, stream>>>(w_fc, wfcT_b, ODIM, HDIM);
  k_gemm_bt<true, false><<<dim3(G3/64, HDIM/128), 256, 0, stream>>>(wih_b, wfcT_b, nullptr, wcomb, G3, HDIM, ODIM);
  k_bcomb<<<G3/4, 256, 0, stream>>>(w_ih, b_ih, b_fc, bcomb);

  if (big) {
    // sentinel-fill the exchange buffer (REQUIRED every call: harness does
    // not re-poison between replays; protocol self-syncs on 0xFF)
    hipMemsetAsync(hseq, 0xFF, (size_t)TLEN*BDIM*HDIM*2, stream);
    // gi0 = src0 @ w_ih^T + b_ih  (f32, exact input for step 0)
    k_gemm_bt<false, true><<<dim3(BDIM/64, G3/128), 256, 0, stream>>>(
        src0_b, wih_b, b_ih, gi0, BDIM, G3, ODIM);
    k_gru_persist<<<256, 256, 0, stream>>>(h0_b, wcomb, whh_b, bcomb, b_hh,
                                           gi0, hidden,
                                           (unsigned long long*)hseq);
    // batched output GEMM over block-layout hseq
    k_gemm_hseq<<<dim3(TLEN*BDIM/64, ODIM/128), 256, 0, stream>>>(
        (const unsigned long long*)hseq, wfc_b, b_fc, out);
  } else {
    for (int t = 0; t < TLEN; t++) {
      const unsigned short* aprev = (t == 0) ? h0_b : hpp + (size_t)((t-1)&1)*BDIM*HDIM;
      unsigned short* hs_cur = hpp + (size_t)(t&1)*BDIM*HDIM;
      const float* hprev_f = (t == 0) ? hidden : ((t & 1) ? hbuf0 : hbuf1);
      float* hout_f = (t & 1) ? hbuf1 : hbuf0;
      if (t == 0) {
        k_gru_step<<<256, 256, 0, stream>>>(src0_b, ODIM, wih_b, b_ih,
            aprev, whh_b, b_hh, hprev_f, hout_f, hs_cur, 0);
      } else {
        k_gru_step<<<256, 256, 0, stream>>>(aprev, HDIM, wcomb, bcomb,
            aprev, whh_b, b_hh, hprev_f, hout_f, hs_cur, 1);
      }
      k_gemm_bt<false, true><<<dim3(BDIM/64, ODIM/128), 256, 0, stream>>>(
          hs_cur, wfc_b, b_fc, out + (size_t)t*BDIM*ODIM, BDIM, ODIM, HDIM);
    }
  }
}